// Round 10
// baseline (242.751 us; speedup 1.0000x reference)
//
#include <hip/hip_runtime.h>
#include <hip/hip_bf16.h>
#include <stdint.h>

// Problem constants: B=4, N=M=2048, C=512, H=4, D_QK=256, D_V=128
#define SCALE_F 0.08838834764831845f  // 1/sqrt(128)
#define LOG2E_F 1.4426950408889634f

typedef __attribute__((ext_vector_type(8))) short short8;
typedef __attribute__((ext_vector_type(4))) float f32x4;
typedef __attribute__((ext_vector_type(16))) float f32x16;
typedef __attribute__((ext_vector_type(2))) unsigned int uint2v;

__device__ __forceinline__ void g2l16(const void* g, void* l) {
  __builtin_amdgcn_global_load_lds(
      (const __attribute__((address_space(1))) void*)g,
      (__attribute__((address_space(3))) void*)l, 16, 0, 0);
}

// pack two f32 -> one dword of 2x bf16 (compiler emits v_cvt_pk_bf16_f32)
__device__ __forceinline__ unsigned pkbf(float a, float b) {
  union { __hip_bfloat16 h[2]; unsigned u; } o;
  o.h[0] = __float2bfloat16(a); o.h[1] = __float2bfloat16(b);
  return o.u;
}

// RAW v_exp_f32 (2^x). Precise exp2f lowers to ~5 VALU ops (denormal guards);
// our inputs are bounded (|s| <= ~16) so the bare instruction is exact enough.
__device__ __forceinline__ float fexp2(float x) {
#if __has_builtin(__builtin_amdgcn_exp2f)
  return __builtin_amdgcn_exp2f(x);
#else
  float r; asm("v_exp_f32 %0, %1" : "=v"(r) : "v"(x)); return r;
#endif
}

// ---------------- fp32 -> bf16 conversion (x, W_qkv, W_proj only) ------------
__global__ __launch_bounds__(256) void convert_all(
    const float* __restrict__ x, const float* __restrict__ wqkv,
    const float* __restrict__ wproj,
    __hip_bfloat16* __restrict__ ab, __hip_bfloat16* __restrict__ wb,
    __hip_bfloat16* __restrict__ wpb)
{
  size_t qi = (size_t)blockIdx.x * 256 + threadIdx.x;  // quad index, <1245184
  const float* src; __hip_bfloat16* dst; size_t off;
  if (qi < 1048576)      { src = x;     dst = ab;  off = qi; }
  else if (qi < 1179648) { src = wqkv;  dst = wb;  off = qi - 1048576; }
  else                   { src = wproj; dst = wpb; off = qi - 1179648; }
  float4 v = ((const float4*)src)[off];
  union { __hip_bfloat16 h4[4]; uint2 u; } o;
  o.h4[0] = __float2bfloat16(v.x); o.h4[1] = __float2bfloat16(v.y);
  o.h4[2] = __float2bfloat16(v.z); o.h4[3] = __float2bfloat16(v.w);
  ((uint2*)dst)[off] = o.u;
}

// ---------------- V transpose + ctx bf16: ctx -> vt (bh,d,m) AND abctx -------
__global__ __launch_bounds__(256) void transpose_v(
    const float* __restrict__ ctx, __hip_bfloat16* __restrict__ vt,
    __hip_bfloat16* __restrict__ abctx)
{
  __shared__ float tile[128][33];
  const int bid = blockIdx.x;          // B*H*64 = 1024
  const int mt = bid & 63;             // 32-row ctx tile
  const int bh = bid >> 6;             // b*4+h
  const int h = bh & 3, b = bh >> 2;
  const int tid = threadIdx.x;
  for (int i = 0; i < 16; ++i) {       // coalesced read along d
    int idx = i * 256 + tid;
    int mm = idx >> 7, d = idx & 127;
    tile[d][mm] = ctx[((size_t)b * 2048 + mt * 32 + mm) * 512 + h * 128 + d];
  }
  __syncthreads();
  for (int i = 0; i < 16; ++i) {       // coalesced write along m (vt)
    int idx = i * 256 + tid;
    int d = idx >> 5, mm = idx & 31;
    vt[((size_t)bh * 128 + d) * 2048 + mt * 32 + mm] = __float2bfloat16(tile[d][mm]);
  }
  for (int i = 0; i < 16; ++i) {       // coalesced bf16 row copy (abctx)
    int idx = i * 256 + tid;
    int mm = idx >> 7, d = idx & 127;
    abctx[((size_t)b * 2048 + mt * 32 + mm) * 512 + h * 128 + d] =
        __float2bfloat16(tile[d][mm]);
  }
}

// ---------------- fused QKV GEMM + per-head l2norm -> bf16 qn/kn -------------
// v3: BM=64 x BN=256 (one head), grid 1024, quadrant wave layout: 8 ds_read
// per 16 MFMA, acc 64 AGPR. Cross-wave row-norms via sNorm LDS. Q side folds
// radius^2*SCALE*log2e (attn uses raw exp2).
__global__ __launch_bounds__(256) void gemm_qkv(
    const __hip_bfloat16* __restrict__ A,   // 16384 x 512 (x rows then ctx rows)
    const __hip_bfloat16* __restrict__ Bw,  // 1024 x 512 (W_qkv bf16)
    const float* __restrict__ radius,
    __hip_bfloat16* __restrict__ qn, __hip_bfloat16* __restrict__ kn)
{
  __shared__ __hip_bfloat16 sAB[320 * 32];   // 20KB: sA 64x32 @0, sB 256x32
  __shared__ float sNorm[4][64];             // per-wave row-ssq partials (1KB)
  __hip_bfloat16* sA = sAB;
  __hip_bfloat16* sB = sAB + 64 * 32;
  const int tid = threadIdx.x;
  const int wave = tid >> 6, lane = tid & 63;
  const int ln = lane & 15, q4 = lane >> 4;
  const int ro = blockIdx.x >> 2;            // [0,256) 64-row tile
  const int co = blockIdx.x & 3;             // head index
  const __hip_bfloat16* Ab = A + (size_t)ro * 64 * 512;
  const __hip_bfloat16* Bb = Bw + (size_t)co * 256 * 512;
  const int row0 = tid >> 2, p0 = tid & 3;
  f32x4 acc[4][4] = {};                      // [mi: row 16s][ni: col 16s]
  for (int k0 = 0; k0 < 512; k0 += 32) {
    g2l16(Ab + (size_t)row0 * 512 + k0 + p0 * 8, (char*)sA + tid * 16);
#pragma unroll
    for (int i = 0; i < 4; ++i)
      g2l16(Bb + (size_t)(i * 64 + row0) * 512 + k0 + p0 * 8,
            (char*)sB + (i * 256 + tid) * 16);
    __syncthreads();
    short8 af[4], bfr[4];
#pragma unroll
    for (int mi = 0; mi < 4; ++mi)
      af[mi] = *(const short8*)(sA + (mi * 16 + ln) * 32 + q4 * 8);
#pragma unroll
    for (int ni = 0; ni < 4; ++ni)
      bfr[ni] = *(const short8*)(sB + (wave * 64 + ni * 16 + ln) * 32 + q4 * 8);
#pragma unroll
    for (int mi = 0; mi < 4; ++mi)
#pragma unroll
      for (int ni = 0; ni < 4; ++ni)
        acc[mi][ni] = __builtin_amdgcn_mfma_f32_16x16x32_bf16(af[mi], bfr[ni], acc[mi][ni], 0, 0, 0);
    __syncthreads();
  }
  const float rad = radius[co];
  const int grow0 = ro * 64;                 // 8192 % 64 == 0: no q/k straddle
  const bool isq = grow0 < 8192;
  const int rl = isq ? grow0 : grow0 - 8192;
  const float qfac = isq ? rad * rad * SCALE_F * LOG2E_F : 1.0f;
#pragma unroll
  for (int mi = 0; mi < 4; ++mi)
#pragma unroll
    for (int r = 0; r < 4; ++r) {
      float ss = acc[mi][0][r] * acc[mi][0][r] + acc[mi][1][r] * acc[mi][1][r]
               + acc[mi][2][r] * acc[mi][2][r] + acc[mi][3][r] * acc[mi][3][r];
      ss += __shfl_xor(ss, 1); ss += __shfl_xor(ss, 2);
      ss += __shfl_xor(ss, 4); ss += __shfl_xor(ss, 8);
      if (ln == 0) sNorm[wave][mi * 16 + q4 * 4 + r] = ss;
    }
  __syncthreads();
  float scl[4][4];
#pragma unroll
  for (int mi = 0; mi < 4; ++mi)
#pragma unroll
    for (int r = 0; r < 4; ++r) {
      int row = mi * 16 + q4 * 4 + r;
      float tot = sNorm[0][row] + sNorm[1][row] + sNorm[2][row] + sNorm[3][row];
      scl[mi][r] = qfac / fmaxf(sqrtf(tot), 1e-12f);
    }
  __hip_bfloat16* dstT = (isq ? qn : kn) +
      ((size_t)((rl >> 11) * 4 + co) * 2048 + (rl & 2047)) * 256;
  __hip_bfloat16* sE = sAB;                  // 32x264 bf16 = 16.9KB <= 20KB
#pragma unroll
  for (int c = 0; c < 2; ++c) {              // chunk c = block rows c*32..+31
#pragma unroll
    for (int mi2 = 0; mi2 < 2; ++mi2) {
      int mi = c * 2 + mi2;
#pragma unroll
      for (int r = 0; r < 4; ++r) {
        int lr = mi2 * 16 + q4 * 4 + r;      // row within chunk [0,32)
#pragma unroll
        for (int ni = 0; ni < 4; ++ni)
          sE[lr * 264 + wave * 64 + ni * 16 + ln] =
              __float2bfloat16(acc[mi][ni][r] * scl[mi][r]);
      }
    }
    __syncthreads();
#pragma unroll
    for (int p = 0; p < 4; ++p) {
      int idx = p * 256 + tid;               // 1024 short8 = 32x256
      int rr = idx >> 5, c8 = idx & 31;
      short8 v = *(const short8*)(sE + rr * 264 + c8 * 8);
      *(short8*)(dstT + (size_t)(c * 32 + rr) * 256 + c8 * 8) = v;
    }
    __syncthreads();
  }
}

// ---------------- final projection GEMM: 128x64 tiles, 2 blocks/CU -----------
__global__ __launch_bounds__(256) void gemm_proj(
    const __hip_bfloat16* __restrict__ A,   // 8192 x 512 (ob)
    const __hip_bfloat16* __restrict__ B,   // 512 x 512 (W_proj bf16, NT)
    float* __restrict__ C)                  // 8192 x 512 fp32
{
  __shared__ __hip_bfloat16 sA[128 * 32];
  __shared__ __hip_bfloat16 sB[64 * 32];
  const int tid = threadIdx.x;
  const int wave = tid >> 6, lane = tid & 63;
  const int ln = lane & 15, q = lane >> 4;
  const int br = (blockIdx.x >> 3) * 128;
  const int bo = (blockIdx.x & 7) * 64;
  const int wr = (wave >> 1) * 64, wc = (wave & 1) * 32;
  const int row0 = tid >> 2, p0 = tid & 3;
  f32x4 acc[4][2] = {};
  for (int k0 = 0; k0 < 512; k0 += 32) {
    g2l16(A + (size_t)(br + row0) * 512 + k0 + p0 * 8, (char*)sA + tid * 16);
    g2l16(A + (size_t)(br + 64 + row0) * 512 + k0 + p0 * 8,
          (char*)sA + (256 + tid) * 16);
    g2l16(B + (size_t)(bo + row0) * 512 + k0 + p0 * 8, (char*)sB + tid * 16);
    __syncthreads();
    short8 af[4], bfr[2];
#pragma unroll
    for (int mi = 0; mi < 4; ++mi)
      af[mi] = *(const short8*)(sA + (wr + mi * 16 + ln) * 32 + q * 8);
#pragma unroll
    for (int ni = 0; ni < 2; ++ni)
      bfr[ni] = *(const short8*)(sB + (wc + ni * 16 + ln) * 32 + q * 8);
#pragma unroll
    for (int mi = 0; mi < 4; ++mi)
#pragma unroll
      for (int ni = 0; ni < 2; ++ni)
        acc[mi][ni] = __builtin_amdgcn_mfma_f32_16x16x32_bf16(af[mi], bfr[ni], acc[mi][ni], 0, 0, 0);
    __syncthreads();
  }
#pragma unroll
  for (int mi = 0; mi < 4; ++mi)
#pragma unroll
    for (int ni = 0; ni < 2; ++ni) {
      int rg = br + wr + mi * 16 + q * 4;
      int cg = bo + wc + ni * 16 + ln;
#pragma unroll
      for (int r = 0; r < 4; ++r)
        C[(size_t)(rg + r) * 512 + cg] = acc[mi][ni][r];
    }
}

// stage one 32-ctx tile of K (4 loads) + V (2 loads) per thread
__device__ __forceinline__ void stage_kv(
    const __hip_bfloat16* __restrict__ Kp, const __hip_bfloat16* __restrict__ Vp,
    int mrow, __hip_bfloat16* dK, __hip_bfloat16* dV, int tid)
{
#pragma unroll
  for (int t = 0; t < 4; ++t) {
    int D = t * 256 + tid, row = D >> 5, cc = D & 31;
    g2l16(Kp + (size_t)(mrow + row) * 256 + ((cc ^ (row & 7)) << 3),
          (char*)dK + D * 16);
  }
#pragma unroll
  for (int t = 0; t < 2; ++t) {
    int D = t * 256 + tid, rd = D >> 2, cc = D & 3;
    g2l16(Vp + (size_t)rd * 2048 + mrow + ((cc ^ ((rd >> 1) & 3)) << 3),
          (char*)dV + D * 16);
  }
}

// QK^T step: S^T = K Q^T, two independent 8-deep MFMA chains
__device__ __forceinline__ void qk_step(
    const __hip_bfloat16* __restrict__ sKc, const short8* qf,
    int m32, int hi, f32x16& sa, f32x16& sb)
{
  for (int j = 0; j < 16; ++j) { sa[j] = 0.f; sb[j] = 0.f; }
#pragma unroll
  for (int kk = 0; kk < 8; ++kk) {
    int ca = kk * 2 + hi, cb = (kk + 8) * 2 + hi;
    short8 kfa = *(const short8*)(sKc + m32 * 256 + ((ca ^ (m32 & 7)) << 3));
    short8 kfb = *(const short8*)(sKc + m32 * 256 + ((cb ^ (m32 & 7)) << 3));
    sa = __builtin_amdgcn_mfma_f32_32x32x16_bf16(kfa, qf[kk], sa, 0, 0, 0);
    sb = __builtin_amdgcn_mfma_f32_32x32x16_bf16(kfb, qf[kk + 8], sb, 0, 0, 0);
  }
}

// softmax (raw exp2) + in-register P-frag build + PV accumulate
__device__ __forceinline__ void smpv_step(
    const f32x16& sa, const f32x16& sb, const __hip_bfloat16* __restrict__ sVc,
    int m32, int hi, f32x16* oacc, float& denom)
{
  union { unsigned u[4]; short8 s; } ua, ub;
  {
    float e0, e1, e2, e3;
    unsigned u0, u1, u2, u3;
    e0 = fexp2(sa[0] + sb[0]); e1 = fexp2(sa[1] + sb[1]);
    e2 = fexp2(sa[2] + sb[2]); e3 = fexp2(sa[3] + sb[3]);
    denom += (e0 + e1) + (e2 + e3);
    u0 = pkbf(e0, e1); u1 = pkbf(e2, e3);
    e0 = fexp2(sa[4] + sb[4]); e1 = fexp2(sa[5] + sb[5]);
    e2 = fexp2(sa[6] + sb[6]); e3 = fexp2(sa[7] + sb[7]);
    denom += (e0 + e1) + (e2 + e3);
    u2 = pkbf(e0, e1); u3 = pkbf(e2, e3);
    uint2v s0 = __builtin_amdgcn_permlane32_swap(u0, u2, false, false);
    uint2v s1 = __builtin_amdgcn_permlane32_swap(u1, u3, false, false);
    ua.u[0] = s0.x; ua.u[1] = s1.x; ua.u[2] = s0.y; ua.u[3] = s1.y;
    e0 = fexp2(sa[8] + sb[8]);   e1 = fexp2(sa[9] + sb[9]);
    e2 = fexp2(sa[10] + sb[10]); e3 = fexp2(sa[11] + sb[11]);
    denom += (e0 + e1) + (e2 + e3);
    u0 = pkbf(e0, e1); u1 = pkbf(e2, e3);
    e0 = fexp2(sa[12] + sb[12]); e1 = fexp2(sa[13] + sb[13]);
    e2 = fexp2(sa[14] + sb[14]); e3 = fexp2(sa[15] + sb[15]);
    denom += (e0 + e1) + (e2 + e3);
    u2 = pkbf(e0, e1); u3 = pkbf(e2, e3);
    uint2v s2 = __builtin_amdgcn_permlane32_swap(u0, u2, false, false);
    uint2v s3 = __builtin_amdgcn_permlane32_swap(u1, u3, false, false);
    ub.u[0] = s2.x; ub.u[1] = s3.x; ub.u[2] = s2.y; ub.u[3] = s3.y;
  }
#pragma unroll
  for (int kc = 0; kc < 2; ++kc) {
    short8 pf = kc ? ub.s : ua.s;
#pragma unroll
    for (int vi = 0; vi < 4; ++vi) {
      int rd = vi * 32 + m32;
      int c = kc * 2 + hi;
      short8 vf = *(const short8*)(sVc + rd * 32 + ((c ^ ((rd >> 1) & 3)) << 3));
      oacc[vi] = __builtin_amdgcn_mfma_f32_32x32x16_bf16(vf, pf, oacc[vi], 0, 0, 0);
    }
  }
}

// ---------------- flash attention v11b: T15 2-deep pipeline, triple buffer ---
// Same schedule as v11; compile fix: no local array of LDS pointers (hipcc
// can't static-init addrspacecast) -- index __shared__ arrays directly with
// runtime phase ints (plain LDS address arithmetic).
// Per half-iteration: {vmcnt(0); s_barrier; stage(it+2); QK(it+1); SM/PV(it)}.
// Barrier proof: stage(n) writes buf[n%3]; its last readers QK(n-2)/PV(n-3)
// precede the previous half's barrier; stage is issued after this half's
// barrier. vmcnt(0) before the barrier publishes each wave's prior staging.
__global__ __launch_bounds__(256, 2) void attn(
    const __hip_bfloat16* __restrict__ qn,  // (bh, 2048, 256), pre-scaled log2e
    const __hip_bfloat16* __restrict__ kn,  // (bh, 2048, 256)
    const __hip_bfloat16* __restrict__ vt,  // (bh, 128, 2048)
    float* __restrict__ Op,                 // (half, bh, 2048, 128) fp32
    float* __restrict__ den)                // (half, bh, 2048) fp32
{
  __shared__ __hip_bfloat16 sK[3][32 * 256];  // 16KB each; swz c^=(row&7)
  __shared__ __hip_bfloat16 sV[3][128 * 32];  // 8KB each; swz c^=((row>>1)&3)
  const int tid = threadIdx.x, wave = tid >> 6, lane = tid & 63;
  const int m32 = lane & 31, hi = lane >> 5;
  const int i = blockIdx.x;
  const int bh = (i & 7) + 8 * ((i >> 3) & 1);
  const int half = (i >> 4) & 1;
  const int nt = i >> 5;                      // [0,16)
  const int mbase = half * 1024;
  const __hip_bfloat16* Q = qn + ((size_t)bh * 2048 + nt * 128 + wave * 32) * 256;
  const __hip_bfloat16* Kp = kn + (size_t)bh * 2048 * 256;
  const __hip_bfloat16* Vp = vt + (size_t)bh * 128 * 2048;

  short8 qf[16];
  for (int kk = 0; kk < 16; ++kk)
    qf[kk] = *(const short8*)(Q + m32 * 256 + kk * 16 + hi * 8);

  f32x16 oacc[4];                 // O^T: rows d = vi*32+cr(reg,hi), col q = m32
  for (int v = 0; v < 4; ++v)
    for (int j = 0; j < 16; ++j) oacc[v][j] = 0.f;
  float denom = 0.f;

  int p0 = 0, p1 = 1, p2 = 2;     // p0 = it%3, p1 = (it+1)%3, p2 = (it+2)%3

  // prologue: stage tiles 0,1; drain; QK(0)
  stage_kv(Kp, Vp, mbase,      sK[0], sV[0], tid);
  stage_kv(Kp, Vp, mbase + 32, sK[1], sV[1], tid);
  asm volatile("s_waitcnt vmcnt(0)" ::: "memory");
  __builtin_amdgcn_s_barrier();
  f32x16 saE, sbE, saO, sbO;
  qk_step(sK[0], qf, m32, hi, saE, sbE);

  for (int it = 0; it < 32; it += 2) {
    // ---- half A: stage(it+2) -> p2, QK(it+1) from p1, SM/PV(it) from p0
    asm volatile("s_waitcnt vmcnt(0)" ::: "memory");
    __builtin_amdgcn_s_barrier();
    if (it + 2 < 32)
      stage_kv(Kp, Vp, mbase + (it + 2) * 32, sK[p2], sV[p2], tid);
    qk_step(sK[p1], qf, m32, hi, saO, sbO);
    smpv_step(saE, sbE, sV[p0], m32, hi, oacc, denom);
    // ---- half B: stage(it+3) -> p0, QK(it+2) from p2, SM/PV(it+1) from p1
    asm volatile("s_waitcnt vmcnt(0)" ::: "memory");
    __builtin_amdgcn_s_barrier();
    if (it + 3 < 32)
      stage_kv(Kp, Vp, mbase + (it + 3) * 32, sK[p0], sV[p0], tid);
    if (it + 2 < 32)
      qk_step(sK[p2], qf, m32, hi, saE, sbE);
    smpv_step(saO, sbO, sV[p1], m32, hi, oacc, denom);
    // rotate: next it%3 = old p2
    int t = p0; p0 = p2; p2 = p1; p1 = t;
  }

  // denom for q=m32: hi=0 and hi=1 lanes hold complementary ctx subsets
  float dfull = denom + __shfl_xor(denom, 32);
  float* Opb = Op + (size_t)(half * 16 + bh) * 2048 * 128;
  float* denb = den + (size_t)(half * 16 + bh) * 2048;
  const int rbase = nt * 128 + wave * 32;
  if (hi == 0) denb[rbase + m32] = dfull;
  // O^T (lane=q, regs=d) -> coalesced Op[row=q][d] via per-wave 32x33 LDS tile
  float* sc_ = (float*)(&sK[0][0]) + wave * 1056;   // 4.2KB/wave, in dead sK
#pragma unroll
  for (int vi = 0; vi < 4; ++vi) {
#pragma unroll
    for (int reg = 0; reg < 16; ++reg) {
      int dL = (reg & 3) + 8 * (reg >> 2) + 4 * hi;
      sc_[m32 * 33 + dL] = oacc[vi][reg];
    }
    asm volatile("s_waitcnt lgkmcnt(0)" ::: "memory");  // wave-local visibility
#pragma unroll
    for (int qq = 0; qq < 16; ++qq) {
      int qr = qq * 2 + hi;
      Opb[(size_t)(rbase + qr) * 128 + vi * 32 + m32] = sc_[qr * 33 + m32];
    }
    asm volatile("s_waitcnt lgkmcnt(0)" ::: "memory");  // reads done before reuse
  }
}

// ---------------- combine ctx halves -> bf16 ob ------------------------------
__global__ __launch_bounds__(256) void combine(
    const float* __restrict__ Op, const float* __restrict__ den,
    __hip_bfloat16* __restrict__ ob)
{
  int qi = blockIdx.x * 256 + threadIdx.x;   // 1,048,576 float4-quads
  int r = qi >> 5;
  int dq = qi & 31;
  int bh = r >> 11, n = r & 2047, b = bh >> 2, h = bh & 3;
  float4 o0 = ((const float4*)Op)[qi];
  float4 o1 = ((const float4*)(Op + 4194304))[qi];
  float inv = 1.0f / (den[r] + den[32768 + r]);
  union { __hip_bfloat16 h4[4]; uint2 u; } o;
  o.h4[0] = __float2bfloat16((o0.x + o1.x) * inv);
  o.h4[1] = __float2bfloat16((o0.y + o1.y) * inv);
  o.h4[2] = __float2bfloat16((o0.z + o1.z) * inv);
  o.h4[3] = __float2bfloat16((o0.w + o1.w) * inv);
  *(uint2*)&ob[((size_t)b * 2048 + n) * 512 + h * 128 + dq * 4] = o.u;
}

// ---------------- launch ------------------------------------------------------
extern "C" void kernel_launch(void* const* d_in, const int* in_sizes, int n_in,
                              void* d_out, int out_size, void* d_ws, size_t ws_size,
                              hipStream_t stream) {
  const float* x      = (const float*)d_in[0];
  const float* ctx    = (const float*)d_in[1];
  const float* wqkv   = (const float*)d_in[2];
  const float* wproj  = (const float*)d_in[3];
  const float* radius = (const float*)d_in[4];
  char* ws = (char*)d_ws;
  __hip_bfloat16* ab  = (__hip_bfloat16*)(ws);              // 16 MB (x+ctx bf16)
  __hip_bfloat16* wb  = (__hip_bfloat16*)(ws + 16777216);   // 1 MB
  __hip_bfloat16* wpb = (__hip_bfloat16*)(ws + 17825792);   // 0.5 MB
  float*          Op  = (float*)(ws + 18350080);            // 32 MB: 2 half partials
  float*          den = (float*)(ws + 18350080 + 33554432); // 256 KB partial denom
  __hip_bfloat16* qn  = (__hip_bfloat16*)(ws + 85458944);   // 16 MB
  __hip_bfloat16* kn  = (__hip_bfloat16*)(ws + 102236160);  // 16 MB
  __hip_bfloat16* vt  = (__hip_bfloat16*)(ws + 119013376);  // 8 MB
  __hip_bfloat16* ob  = (__hip_bfloat16*)(ws + 127401984);  // 8 MB
  float* out = (float*)d_out;

  convert_all<<<4864, 256, 0, stream>>>(x, wqkv, wproj, ab, wb, wpb);
  transpose_v<<<1024, 256, 0, stream>>>(ctx, vt, ab + 4194304);
  gemm_qkv<<<1024, 256, 0, stream>>>(ab, wb, radius, qn, kn);   // fused norm+log2e
  attn<<<512, 256, 0, stream>>>(qn, kn, vt, Op, den);
  combine<<<4096, 256, 0, stream>>>(Op, den, ob);
  gemm_proj<<<512, 256, 0, stream>>>(ob, wpb, out);             // 8192x512, 2/CU
}

// Round 11
// 210.837 us; speedup vs baseline: 1.1514x; 1.1514x over previous
//
#include <hip/hip_runtime.h>
#include <hip/hip_bf16.h>
#include <stdint.h>

// Problem constants: B=4, N=M=2048, C=512, H=4, D_QK=256, D_V=128
#define SCALE_F 0.08838834764831845f  // 1/sqrt(128)
#define LOG2E_F 1.4426950408889634f

typedef __attribute__((ext_vector_type(8))) short short8;
typedef __attribute__((ext_vector_type(4))) float f32x4;
typedef __attribute__((ext_vector_type(16))) float f32x16;
typedef __attribute__((ext_vector_type(2))) unsigned int uint2v;

__device__ __forceinline__ void g2l16(const void* g, void* l) {
  __builtin_amdgcn_global_load_lds(
      (const __attribute__((address_space(1))) void*)g,
      (__attribute__((address_space(3))) void*)l, 16, 0, 0);
}

// pack two f32 -> one dword of 2x bf16 (compiler emits v_cvt_pk_bf16_f32)
__device__ __forceinline__ unsigned pkbf(float a, float b) {
  union { __hip_bfloat16 h[2]; unsigned u; } o;
  o.h[0] = __float2bfloat16(a); o.h[1] = __float2bfloat16(b);
  return o.u;
}

// RAW v_exp_f32 (2^x). Precise exp2f lowers to ~5 VALU ops (denormal guards);
// our inputs are bounded (|s| <= ~16) so the bare instruction is exact enough.
__device__ __forceinline__ float fexp2(float x) {
#if __has_builtin(__builtin_amdgcn_exp2f)
  return __builtin_amdgcn_exp2f(x);
#else
  float r; asm("v_exp_f32 %0, %1" : "=v"(r) : "v"(x)); return r;
#endif
}

// ---------------- fp32 -> bf16 conversion (x, W_qkv, W_proj only) ------------
__global__ __launch_bounds__(256) void convert_all(
    const float* __restrict__ x, const float* __restrict__ wqkv,
    const float* __restrict__ wproj,
    __hip_bfloat16* __restrict__ ab, __hip_bfloat16* __restrict__ wb,
    __hip_bfloat16* __restrict__ wpb)
{
  size_t qi = (size_t)blockIdx.x * 256 + threadIdx.x;  // quad index, <1245184
  const float* src; __hip_bfloat16* dst; size_t off;
  if (qi < 1048576)      { src = x;     dst = ab;  off = qi; }
  else if (qi < 1179648) { src = wqkv;  dst = wb;  off = qi - 1048576; }
  else                   { src = wproj; dst = wpb; off = qi - 1179648; }
  float4 v = ((const float4*)src)[off];
  union { __hip_bfloat16 h4[4]; uint2 u; } o;
  o.h4[0] = __float2bfloat16(v.x); o.h4[1] = __float2bfloat16(v.y);
  o.h4[2] = __float2bfloat16(v.z); o.h4[3] = __float2bfloat16(v.w);
  ((uint2*)dst)[off] = o.u;
}

// ---------------- V transpose + ctx bf16: ctx -> vt (bh,d,m) AND abctx -------
__global__ __launch_bounds__(256) void transpose_v(
    const float* __restrict__ ctx, __hip_bfloat16* __restrict__ vt,
    __hip_bfloat16* __restrict__ abctx)
{
  __shared__ float tile[128][33];
  const int bid = blockIdx.x;          // B*H*64 = 1024
  const int mt = bid & 63;             // 32-row ctx tile
  const int bh = bid >> 6;             // b*4+h
  const int h = bh & 3, b = bh >> 2;
  const int tid = threadIdx.x;
  for (int i = 0; i < 16; ++i) {       // coalesced read along d
    int idx = i * 256 + tid;
    int mm = idx >> 7, d = idx & 127;
    tile[d][mm] = ctx[((size_t)b * 2048 + mt * 32 + mm) * 512 + h * 128 + d];
  }
  __syncthreads();
  for (int i = 0; i < 16; ++i) {       // coalesced write along m (vt)
    int idx = i * 256 + tid;
    int d = idx >> 5, mm = idx & 31;
    vt[((size_t)bh * 128 + d) * 2048 + mt * 32 + mm] = __float2bfloat16(tile[d][mm]);
  }
  for (int i = 0; i < 16; ++i) {       // coalesced bf16 row copy (abctx)
    int idx = i * 256 + tid;
    int mm = idx >> 7, d = idx & 127;
    abctx[((size_t)b * 2048 + mt * 32 + mm) * 512 + h * 128 + d] =
        __float2bfloat16(tile[d][mm]);
  }
}

// ---------------- fused QKV GEMM + per-head l2norm -> bf16 qn/kn -------------
// v3: BM=64 x BN=256 (one head), grid 1024, quadrant wave layout: 8 ds_read
// per 16 MFMA, acc 64 AGPR. Cross-wave row-norms via sNorm LDS. Q side folds
// radius^2*SCALE*log2e (attn uses raw exp2).
__global__ __launch_bounds__(256) void gemm_qkv(
    const __hip_bfloat16* __restrict__ A,   // 16384 x 512 (x rows then ctx rows)
    const __hip_bfloat16* __restrict__ Bw,  // 1024 x 512 (W_qkv bf16)
    const float* __restrict__ radius,
    __hip_bfloat16* __restrict__ qn, __hip_bfloat16* __restrict__ kn)
{
  __shared__ __hip_bfloat16 sAB[320 * 32];   // 20KB: sA 64x32 @0, sB 256x32
  __shared__ float sNorm[4][64];             // per-wave row-ssq partials (1KB)
  __hip_bfloat16* sA = sAB;
  __hip_bfloat16* sB = sAB + 64 * 32;
  const int tid = threadIdx.x;
  const int wave = tid >> 6, lane = tid & 63;
  const int ln = lane & 15, q4 = lane >> 4;
  const int ro = blockIdx.x >> 2;            // [0,256) 64-row tile
  const int co = blockIdx.x & 3;             // head index
  const __hip_bfloat16* Ab = A + (size_t)ro * 64 * 512;
  const __hip_bfloat16* Bb = Bw + (size_t)co * 256 * 512;
  const int row0 = tid >> 2, p0 = tid & 3;
  f32x4 acc[4][4] = {};                      // [mi: row 16s][ni: col 16s]
  for (int k0 = 0; k0 < 512; k0 += 32) {
    g2l16(Ab + (size_t)row0 * 512 + k0 + p0 * 8, (char*)sA + tid * 16);
#pragma unroll
    for (int i = 0; i < 4; ++i)
      g2l16(Bb + (size_t)(i * 64 + row0) * 512 + k0 + p0 * 8,
            (char*)sB + (i * 256 + tid) * 16);
    __syncthreads();
    short8 af[4], bfr[4];
#pragma unroll
    for (int mi = 0; mi < 4; ++mi)
      af[mi] = *(const short8*)(sA + (mi * 16 + ln) * 32 + q4 * 8);
#pragma unroll
    for (int ni = 0; ni < 4; ++ni)
      bfr[ni] = *(const short8*)(sB + (wave * 64 + ni * 16 + ln) * 32 + q4 * 8);
#pragma unroll
    for (int mi = 0; mi < 4; ++mi)
#pragma unroll
      for (int ni = 0; ni < 4; ++ni)
        acc[mi][ni] = __builtin_amdgcn_mfma_f32_16x16x32_bf16(af[mi], bfr[ni], acc[mi][ni], 0, 0, 0);
    __syncthreads();
  }
  const float rad = radius[co];
  const int grow0 = ro * 64;                 // 8192 % 64 == 0: no q/k straddle
  const bool isq = grow0 < 8192;
  const int rl = isq ? grow0 : grow0 - 8192;
  const float qfac = isq ? rad * rad * SCALE_F * LOG2E_F : 1.0f;
#pragma unroll
  for (int mi = 0; mi < 4; ++mi)
#pragma unroll
    for (int r = 0; r < 4; ++r) {
      float ss = acc[mi][0][r] * acc[mi][0][r] + acc[mi][1][r] * acc[mi][1][r]
               + acc[mi][2][r] * acc[mi][2][r] + acc[mi][3][r] * acc[mi][3][r];
      ss += __shfl_xor(ss, 1); ss += __shfl_xor(ss, 2);
      ss += __shfl_xor(ss, 4); ss += __shfl_xor(ss, 8);
      if (ln == 0) sNorm[wave][mi * 16 + q4 * 4 + r] = ss;
    }
  __syncthreads();
  float scl[4][4];
#pragma unroll
  for (int mi = 0; mi < 4; ++mi)
#pragma unroll
    for (int r = 0; r < 4; ++r) {
      int row = mi * 16 + q4 * 4 + r;
      float tot = sNorm[0][row] + sNorm[1][row] + sNorm[2][row] + sNorm[3][row];
      scl[mi][r] = qfac / fmaxf(sqrtf(tot), 1e-12f);
    }
  __hip_bfloat16* dstT = (isq ? qn : kn) +
      ((size_t)((rl >> 11) * 4 + co) * 2048 + (rl & 2047)) * 256;
  __hip_bfloat16* sE = sAB;                  // 32x264 bf16 = 16.9KB <= 20KB
#pragma unroll
  for (int c = 0; c < 2; ++c) {              // chunk c = block rows c*32..+31
#pragma unroll
    for (int mi2 = 0; mi2 < 2; ++mi2) {
      int mi = c * 2 + mi2;
#pragma unroll
      for (int r = 0; r < 4; ++r) {
        int lr = mi2 * 16 + q4 * 4 + r;      // row within chunk [0,32)
#pragma unroll
        for (int ni = 0; ni < 4; ++ni)
          sE[lr * 264 + wave * 64 + ni * 16 + ln] =
              __float2bfloat16(acc[mi][ni][r] * scl[mi][r]);
      }
    }
    __syncthreads();
#pragma unroll
    for (int p = 0; p < 4; ++p) {
      int idx = p * 256 + tid;               // 1024 short8 = 32x256
      int rr = idx >> 5, c8 = idx & 31;
      short8 v = *(const short8*)(sE + rr * 264 + c8 * 8);
      *(short8*)(dstT + (size_t)(c * 32 + rr) * 256 + c8 * 8) = v;
    }
    __syncthreads();
  }
}

// ---------------- final projection GEMM: 128x64 tiles, 2 blocks/CU -----------
__global__ __launch_bounds__(256) void gemm_proj(
    const __hip_bfloat16* __restrict__ A,   // 8192 x 512 (ob)
    const __hip_bfloat16* __restrict__ B,   // 512 x 512 (W_proj bf16, NT)
    float* __restrict__ C)                  // 8192 x 512 fp32
{
  __shared__ __hip_bfloat16 sA[128 * 32];
  __shared__ __hip_bfloat16 sB[64 * 32];
  const int tid = threadIdx.x;
  const int wave = tid >> 6, lane = tid & 63;
  const int ln = lane & 15, q = lane >> 4;
  const int br = (blockIdx.x >> 3) * 128;
  const int bo = (blockIdx.x & 7) * 64;
  const int wr = (wave >> 1) * 64, wc = (wave & 1) * 32;
  const int row0 = tid >> 2, p0 = tid & 3;
  f32x4 acc[4][2] = {};
  for (int k0 = 0; k0 < 512; k0 += 32) {
    g2l16(A + (size_t)(br + row0) * 512 + k0 + p0 * 8, (char*)sA + tid * 16);
    g2l16(A + (size_t)(br + 64 + row0) * 512 + k0 + p0 * 8,
          (char*)sA + (256 + tid) * 16);
    g2l16(B + (size_t)(bo + row0) * 512 + k0 + p0 * 8, (char*)sB + tid * 16);
    __syncthreads();
    short8 af[4], bfr[2];
#pragma unroll
    for (int mi = 0; mi < 4; ++mi)
      af[mi] = *(const short8*)(sA + (wr + mi * 16 + ln) * 32 + q * 8);
#pragma unroll
    for (int ni = 0; ni < 2; ++ni)
      bfr[ni] = *(const short8*)(sB + (wc + ni * 16 + ln) * 32 + q * 8);
#pragma unroll
    for (int mi = 0; mi < 4; ++mi)
#pragma unroll
      for (int ni = 0; ni < 2; ++ni)
        acc[mi][ni] = __builtin_amdgcn_mfma_f32_16x16x32_bf16(af[mi], bfr[ni], acc[mi][ni], 0, 0, 0);
    __syncthreads();
  }
#pragma unroll
  for (int mi = 0; mi < 4; ++mi)
#pragma unroll
    for (int ni = 0; ni < 2; ++ni) {
      int rg = br + wr + mi * 16 + q * 4;
      int cg = bo + wc + ni * 16 + ln;
#pragma unroll
      for (int r = 0; r < 4; ++r)
        C[(size_t)(rg + r) * 512 + cg] = acc[mi][ni][r];
    }
}

// ---------------- flash attention v10 (R8-proven, 65.8us): dbuf + raw exp2 ---
// grid 512 = bh(16) x nt(16) x half(2), XCD-swizzled; 2 blocks/CU; dbuf sK/sV;
// swapped-operand QK^T; in-register P via cvt_pk + permlane32_swap. Q carries
// log2e (folded in gemm_qkv) so softmax is a single v_exp_f32 per element.
// [T15/counted-vmcnt/setprio/splits all tried and regressed -- see R5/R6/R10.]
__global__ __launch_bounds__(256, 2) void attn(
    const __hip_bfloat16* __restrict__ qn,  // (bh, 2048, 256), pre-scaled log2e
    const __hip_bfloat16* __restrict__ kn,  // (bh, 2048, 256)
    const __hip_bfloat16* __restrict__ vt,  // (bh, 128, 2048)
    float* __restrict__ Op,                 // (half, bh, 2048, 128) fp32
    float* __restrict__ den)                // (half, bh, 2048) fp32
{
  __shared__ __hip_bfloat16 sK[2][32 * 256];  // 16KB each; swz c^=(row&7)
  __shared__ __hip_bfloat16 sV[2][128 * 32];  // 8KB each; swz c^=((row>>1)&3)
  const int tid = threadIdx.x, wave = tid >> 6, lane = tid & 63;
  const int m32 = lane & 31, hi = lane >> 5;
  // XCD-aware decode: bh constant per XCD (round-robin blockIdx % 8)
  const int i = blockIdx.x;
  const int bh = (i & 7) + 8 * ((i >> 3) & 1);
  const int half = (i >> 4) & 1;
  const int nt = i >> 5;                      // [0,16)
  const int mbase = half * 1024;
  const __hip_bfloat16* Q = qn + ((size_t)bh * 2048 + nt * 128 + wave * 32) * 256;
  const __hip_bfloat16* Kp = kn + (size_t)bh * 2048 * 256;
  const __hip_bfloat16* Vp = vt + (size_t)bh * 128 * 2048;

  // Q B-frags in registers: col=q(m32), k-chunk kk, lane-half hi holds 8 elems
  short8 qf[16];
  for (int kk = 0; kk < 16; ++kk)
    qf[kk] = *(const short8*)(Q + m32 * 256 + kk * 16 + hi * 8);

  f32x16 oacc[4];                 // O^T: rows d = vi*32+cr(reg,hi), col q = m32
  for (int v = 0; v < 4; ++v)
    for (int j = 0; j < 16; ++j) oacc[v][j] = 0.f;
  float denom = 0.f;              // per-lane: sum over this lane's ctx subset

  // stage tile 0 into buffer 0
  for (int t = 0; t < 4; ++t) {
    int D = t * 256 + tid, row = D >> 5, cc = D & 31;
    g2l16(Kp + (size_t)(mbase + row) * 256 + ((cc ^ (row & 7)) << 3),
          (char*)sK[0] + D * 16);
  }
  for (int t = 0; t < 2; ++t) {
    int D = t * 256 + tid, rd = D >> 2, cc = D & 3;
    g2l16(Vp + (size_t)rd * 2048 + mbase + ((cc ^ ((rd >> 1) & 3)) << 3),
          (char*)sV[0] + D * 16);
  }
  __syncthreads();

  for (int it = 0; it < 32; ++it) {
    const int cur = it & 1, nxt = cur ^ 1;
    if (it + 1 < 32) {
      const int m1 = mbase + (it + 1) * 32;
      for (int t = 0; t < 4; ++t) {
        int D = t * 256 + tid, row = D >> 5, cc = D & 31;
        g2l16(Kp + (size_t)(m1 + row) * 256 + ((cc ^ (row & 7)) << 3),
              (char*)sK[nxt] + D * 16);
      }
      for (int t = 0; t < 2; ++t) {
        int D = t * 256 + tid, rd = D >> 2, cc = D & 3;
        g2l16(Vp + (size_t)rd * 2048 + m1 + ((cc ^ ((rd >> 1) & 3)) << 3),
              (char*)sV[nxt] + D * 16);
      }
    }
    // S^T = K Q^T: A=K-frag (row=ctx), B=Q-frag (col=q)
    const __hip_bfloat16* sKc = sK[cur];
    f32x16 sa, sb;
    for (int j = 0; j < 16; ++j) { sa[j] = 0.f; sb[j] = 0.f; }
#pragma unroll
    for (int kk = 0; kk < 8; ++kk) {
      int ca = kk * 2 + hi, cb = (kk + 8) * 2 + hi;
      short8 kfa = *(const short8*)(sKc + m32 * 256 + ((ca ^ (m32 & 7)) << 3));
      short8 kfb = *(const short8*)(sKc + m32 * 256 + ((cb ^ (m32 & 7)) << 3));
      sa = __builtin_amdgcn_mfma_f32_32x32x16_bf16(kfa, qf[kk], sa, 0, 0, 0);
      sb = __builtin_amdgcn_mfma_f32_32x32x16_bf16(kfb, qf[kk + 8], sb, 0, 0, 0);
    }
    // softmax numerator e = 2^s, single v_exp_f32 each; lane's reg r holds ctx
    // row (r&3)+8*(r>>2)+4*hi of S^T; PV B-frags via cvt_pk + permlane32_swap
    union { unsigned u[4]; short8 s; } ua, ub;
    {
      float e0, e1, e2, e3;
      unsigned u0, u1, u2, u3;
      e0 = fexp2(sa[0] + sb[0]); e1 = fexp2(sa[1] + sb[1]);
      e2 = fexp2(sa[2] + sb[2]); e3 = fexp2(sa[3] + sb[3]);
      denom += (e0 + e1) + (e2 + e3);
      u0 = pkbf(e0, e1); u1 = pkbf(e2, e3);
      e0 = fexp2(sa[4] + sb[4]); e1 = fexp2(sa[5] + sb[5]);
      e2 = fexp2(sa[6] + sb[6]); e3 = fexp2(sa[7] + sb[7]);
      denom += (e0 + e1) + (e2 + e3);
      u2 = pkbf(e0, e1); u3 = pkbf(e2, e3);
      uint2v s0 = __builtin_amdgcn_permlane32_swap(u0, u2, false, false);
      uint2v s1 = __builtin_amdgcn_permlane32_swap(u1, u3, false, false);
      ua.u[0] = s0.x; ua.u[1] = s1.x; ua.u[2] = s0.y; ua.u[3] = s1.y;
      e0 = fexp2(sa[8] + sb[8]);   e1 = fexp2(sa[9] + sb[9]);
      e2 = fexp2(sa[10] + sb[10]); e3 = fexp2(sa[11] + sb[11]);
      denom += (e0 + e1) + (e2 + e3);
      u0 = pkbf(e0, e1); u1 = pkbf(e2, e3);
      e0 = fexp2(sa[12] + sb[12]); e1 = fexp2(sa[13] + sb[13]);
      e2 = fexp2(sa[14] + sb[14]); e3 = fexp2(sa[15] + sb[15]);
      denom += (e0 + e1) + (e2 + e3);
      u2 = pkbf(e0, e1); u3 = pkbf(e2, e3);
      uint2v s2 = __builtin_amdgcn_permlane32_swap(u0, u2, false, false);
      uint2v s3 = __builtin_amdgcn_permlane32_swap(u1, u3, false, false);
      ub.u[0] = s2.x; ub.u[1] = s3.x; ub.u[2] = s2.y; ub.u[3] = s3.y;
    }
    // O^T += V^T P : A=V^T-frag (row=d) from LDS, B=in-register P-frag
    const __hip_bfloat16* sVc = sV[cur];
#pragma unroll
    for (int kc = 0; kc < 2; ++kc) {
      short8 pf = kc ? ub.s : ua.s;
#pragma unroll
      for (int vi = 0; vi < 4; ++vi) {
        int rd = vi * 32 + m32;
        int c = kc * 2 + hi;
        short8 vf = *(const short8*)(sVc + rd * 32 + ((c ^ ((rd >> 1) & 3)) << 3));
        oacc[vi] = __builtin_amdgcn_mfma_f32_32x32x16_bf16(vf, pf, oacc[vi], 0, 0, 0);
      }
    }
    __syncthreads();  // drains prefetch vmcnt + guards buffer swap
  }

  // denom for q=m32: hi=0 and hi=1 lanes hold complementary ctx subsets
  float dfull = denom + __shfl_xor(denom, 32);
  float* Opb = Op + (size_t)(half * 16 + bh) * 2048 * 128;
  float* denb = den + (size_t)(half * 16 + bh) * 2048;
  const int rbase = nt * 128 + wave * 32;
  if (hi == 0) denb[rbase + m32] = dfull;
  // O^T (lane=q, regs=d) -> coalesced Op[row=q][d] via per-wave 32x33 LDS tile
  float* sc_ = (float*)(&sK[0][0]) + wave * 1056;   // 4.2KB/wave, in dead sK
#pragma unroll
  for (int vi = 0; vi < 4; ++vi) {
#pragma unroll
    for (int reg = 0; reg < 16; ++reg) {
      int dL = (reg & 3) + 8 * (reg >> 2) + 4 * hi;
      sc_[m32 * 33 + dL] = oacc[vi][reg];
    }
    asm volatile("s_waitcnt lgkmcnt(0)" ::: "memory");  // wave-local visibility
#pragma unroll
    for (int qq = 0; qq < 16; ++qq) {
      int qr = qq * 2 + hi;
      Opb[(size_t)(rbase + qr) * 128 + vi * 32 + m32] = sc_[qr * 33 + m32];
    }
    asm volatile("s_waitcnt lgkmcnt(0)" ::: "memory");  // reads done before reuse
  }
}

// ---------------- combine ctx halves -> bf16 ob ------------------------------
__global__ __launch_bounds__(256) void combine(
    const float* __restrict__ Op, const float* __restrict__ den,
    __hip_bfloat16* __restrict__ ob)
{
  int qi = blockIdx.x * 256 + threadIdx.x;   // 1,048,576 float4-quads
  int r = qi >> 5;
  int dq = qi & 31;
  int bh = r >> 11, n = r & 2047, b = bh >> 2, h = bh & 3;
  float4 o0 = ((const float4*)Op)[qi];
  float4 o1 = ((const float4*)(Op + 4194304))[qi];
  float inv = 1.0f / (den[r] + den[32768 + r]);
  union { __hip_bfloat16 h4[4]; uint2 u; } o;
  o.h4[0] = __float2bfloat16((o0.x + o1.x) * inv);
  o.h4[1] = __float2bfloat16((o0.y + o1.y) * inv);
  o.h4[2] = __float2bfloat16((o0.z + o1.z) * inv);
  o.h4[3] = __float2bfloat16((o0.w + o1.w) * inv);
  *(uint2*)&ob[((size_t)b * 2048 + n) * 512 + h * 128 + dq * 4] = o.u;
}

// ---------------- launch ------------------------------------------------------
extern "C" void kernel_launch(void* const* d_in, const int* in_sizes, int n_in,
                              void* d_out, int out_size, void* d_ws, size_t ws_size,
                              hipStream_t stream) {
  const float* x      = (const float*)d_in[0];
  const float* ctx    = (const float*)d_in[1];
  const float* wqkv   = (const float*)d_in[2];
  const float* wproj  = (const float*)d_in[3];
  const float* radius = (const float*)d_in[4];
  char* ws = (char*)d_ws;
  __hip_bfloat16* ab  = (__hip_bfloat16*)(ws);              // 16 MB (x+ctx bf16)
  __hip_bfloat16* wb  = (__hip_bfloat16*)(ws + 16777216);   // 1 MB
  __hip_bfloat16* wpb = (__hip_bfloat16*)(ws + 17825792);   // 0.5 MB
  float*          Op  = (float*)(ws + 18350080);            // 32 MB: 2 half partials
  float*          den = (float*)(ws + 18350080 + 33554432); // 256 KB partial denom
  __hip_bfloat16* qn  = (__hip_bfloat16*)(ws + 85458944);   // 16 MB
  __hip_bfloat16* kn  = (__hip_bfloat16*)(ws + 102236160);  // 16 MB
  __hip_bfloat16* vt  = (__hip_bfloat16*)(ws + 119013376);  // 8 MB
  __hip_bfloat16* ob  = (__hip_bfloat16*)(ws + 127401984);  // 8 MB
  float* out = (float*)d_out;

  convert_all<<<4864, 256, 0, stream>>>(x, wqkv, wproj, ab, wb, wpb);
  transpose_v<<<1024, 256, 0, stream>>>(ctx, vt, ab + 4194304);
  gemm_qkv<<<1024, 256, 0, stream>>>(ab, wb, radius, qn, kn);   // fused norm+log2e
  attn<<<512, 256, 0, stream>>>(qn, kn, vt, Op, den);
  combine<<<4096, 256, 0, stream>>>(Op, den, ob);
  gemm_proj<<<512, 256, 0, stream>>>(ob, wpb, out);             // 8192x512, 2/CU
}